// Round 10
// baseline (111.686 us; speedup 1.0000x reference)
//
#include <hip/hip_runtime.h>
#include <hip/hip_bf16.h>
#include <math.h>

#define BB    256   // batch
#define LL    256   // seq len
#define NV    14    // vocab
#define EMBD  512
#define H2    128   // L//2
#define OC    256   // branch conv out channels
#define NP    196   // 14*14 ordered token pairs
#define JD    128   // branch linear out
#define MO    64    // manip conv out channels
#define MJ    256   // manip linear out
#define GH    64    // partial h-groups (H2 / NH, NH=2)

// prep block ranges
#define PB_CWT    256                   // 2 br * 4 o-chunks * 32 i-chunks
#define PB_MANIPW 96
#define PB_LINT   64

using s16x8 = __attribute__((ext_vector_type(8))) short;
using f32x4 = __attribute__((ext_vector_type(4))) float;

static __device__ __forceinline__ unsigned short f2bf_rne(float f) {
    unsigned int u = __float_as_uint(f);
    unsigned int r = (u + 0x7FFFu + ((u >> 16) & 1u)) >> 16;
    return (unsigned short)r;
}
static __device__ __forceinline__ float bf2f(unsigned short h) {
    return __uint_as_float(((unsigned int)h) << 16);
}

// ---------- combined prep: cwt (LDS transpose) | manipw | lint ----------
__global__ void k_prep(const float* __restrict__ cw_e, const float* __restrict__ cw_f,
                       const float* __restrict__ mcw, const float* __restrict__ mlw,
                       float* __restrict__ cwT, float* __restrict__ Wc,
                       float* __restrict__ Lint) {
    __shared__ float T[48][66];   // cwt transpose tile
    int bid = blockIdx.x;
    int t = threadIdx.x;
    if (bid < PB_CWT) {                    // cwt: coalesced read + LDS transpose
        int cb = bid;                      // 0..255
        int ic = cb & 31;                  // i-chunk (16 i's)
        int oc = (cb >> 5) & 3;            // o-chunk (64 o's)
        int br = cb >> 7;                  // branch
        int i0 = ic * 16, o0 = oc * 64;
        const float* cw = br ? cw_f : cw_e;
        int ol = t >> 2, part = t & 3;     // o_local 0..63, i-quarter 0..3
        const float* src = cw + ((size_t)(o0 + ol) * EMBD + i0) * 9 + part * 36;
        #pragma unroll
        for (int ii = 0; ii < 4; ++ii)
            #pragma unroll
            for (int kh = 0; kh < 3; ++kh)
                T[kh * 16 + part * 4 + ii][ol] = src[ii * 9 + kh * 3 + 1];
        __syncthreads();
        int lane = t & 63, r0 = t >> 6;
        for (int rr = r0; rr < 48; rr += 4) {
            int kh = rr >> 4, il = rr & 15;
            cwT[(((size_t)(br * 3 + kh)) * EMBD + i0 + il) * OC + o0 + lane] = T[rr][lane];
        }
    } else if (bid < PB_CWT + PB_MANIPW) { // manipw
        int idx = (bid - PB_CWT) * 256 + t;
        int o = idx & 63;
        int i = (idx >> 6) & 127;
        int cls = idx >> 13;
        const float* base = mcw + ((size_t)(o * 128 + i) * 3) * 3 + 1;
        float v = 0.f;
        if (cls != 2) { v += base[3]; v += base[6]; }
        else          { v += base[0]; v += base[3]; }
        if (cls == 1)   v += base[0];
        Wc[idx] = v;
    } else {                                // lint (full interior sum)
        int o = bid - (PB_CWT + PB_MANIPW);   // 0..63
        float s = 0.f;
        for (int h = 1; h <= 126; h++)
            s += mlw[((size_t)(o * H2 + h)) * MJ + t];
        Lint[o * 256 + t] = s;
    }
}

// ---------- pair contributions, full K, q-batch 4, inline pair-max ----------
__global__ __launch_bounds__(256) void k_contrib(
        const float* __restrict__ emb_e, const float* __restrict__ emb_f,
        const float* __restrict__ cwT,
        const float* __restrict__ cb_e, const float* __restrict__ cb_f,
        float* __restrict__ C) {
    int bid = blockIdx.x;               // (br*3+kh)*49+qg
    int qg = bid % 49;
    int kh = (bid / 49) % 3;
    int br = bid / 147;
    int o = threadIdx.x;
    const float* emb = br ? emb_f : emb_e;

    __shared__ float Pl[4][512];
    for (int idx = o; idx < 4 * 512; idx += 256) {
        int row = idx >> 9, col = idx & 511;
        int q = qg * 4 + row;
        int t1 = q / NV, t2 = q % NV;
        Pl[row][col] = fmaxf(emb[t1 * EMBD + col], emb[t2 * EMBD + col]);
    }
    __syncthreads();

    const float* w = cwT + ((size_t)(br * 3 + kh) * EMBD) * OC + o;
    float acc[4] = {0.f, 0.f, 0.f, 0.f};
    #pragma unroll 8
    for (int i = 0; i < 512; i++) {
        float wv = w[(size_t)i * OC];
        #pragma unroll
        for (int qq = 0; qq < 4; qq++) acc[qq] = fmaf(wv, Pl[qq][i], acc[qq]);
    }
    float cbv = (kh == 1) ? (br ? cb_f[o] : cb_e[o]) : 0.f;
    #pragma unroll
    for (int qq = 0; qq < 4; qq++)
        C[(((size_t)br * NP + qg * 4 + qq) * 3 + kh) * OC + o] = acc[qq] + cbv;
}

// ---------- MFMA GEMM: partial[b][hg][j] = sum_{h in grp, o} Y * lw ----------
// M-tile 32, NH=2 h's per block accumulated in-register, grid (64, 8) = 512
// blocks, ~45KB LDS -> 3 blocks/CU. B staged as per-thread k-runs (coalesced
// strided dword loads, packed uint2 LDS writes -> [j][k] layout, no scalar
// b16 transpose writes). X3=1: bf16 hi/lo 3-product split.
template <int X3, int SK, int NH>
__global__ __launch_bounds__(512) void k_gemm(
        const int* __restrict__ tok, const float* __restrict__ C,
        const float* __restrict__ lw, float* __restrict__ partial) {
    constexpr int SPH = 256 / SK;       // stages per h
    constexpr int U   = NH * SPH;       // total stages
    constexpr int KA  = SK / 16;        // A floats per thread
    constexpr int KB  = SK / 4;         // B dwords per thread
    constexpr int PD  = SK + 4;         // LDS row pitch (ushorts)

    __shared__ unsigned short Ah[2][32][PD];
    __shared__ unsigned short Al[X3 ? 2 : 1][X3 ? 32 : 1][X3 ? PD : 1];
    __shared__ unsigned short Bh[2][128][PD];
    __shared__ unsigned short Bl[X3 ? 2 : 1][X3 ? 128 : 1][X3 ? PD : 1];

    const int hg = blockIdx.x;          // h-group 0..63
    const int h0 = hg * NH;
    const int B0 = blockIdx.y * 32;
    const int t  = threadIdx.x;

    // ---- A mapping: row am 0..31, k-chunk kq (KA floats)
    const int am = t >> 4;
    const int kq = (t & 15) * KA;
    const int* tb = tok + (size_t)(B0 + am) * LL;

    // ---- B mapping: j-row jb 0..127, k-run kg (KB dwords)
    const int jb = t & 127;
    const int kg = (t >> 7) * KB;

    const float *r1, *r0, *r2;
    const float* wbase;
    auto setptr = [&](int h) {
        int q1 = tb[2 * h] * NV + tb[2 * h + 1];
        r1 = C + ((size_t)q1 * 3 + 1) * OC + kq;
        r0 = nullptr; r2 = nullptr;
        if (h > 0)      { int q0 = tb[2 * h - 2] * NV + tb[2 * h - 1]; r0 = C + ((size_t)q0 * 3 + 0) * OC + kq; }
        if (h < H2 - 1) { int q2 = tb[2 * h + 2] * NV + tb[2 * h + 3]; r2 = C + ((size_t)q2 * 3 + 2) * OC + kq; }
        wbase = lw + (size_t)h * JD + jb;
    };

    float ya[KA], ybv[KA], ycv[KA], wv[KB];

    auto load = [&](int s) {
        #pragma unroll
        for (int p = 0; p < KA; ++p) {
            ya[p]  = r1[s * SK + p];
            ybv[p] = r0 ? r0[s * SK + p] : 0.f;
            ycv[p] = r2 ? r2[s * SK + p] : 0.f;
        }
        #pragma unroll
        for (int p = 0; p < KB; ++p)
            wv[p] = wbase[(size_t)(s * SK + kg + p) * (H2 * JD)];
    };

    auto store = [&](int buf) {
        // A: pack KA bf16 (+lo) into uint/uint2 (kq*2 bytes is 4/8B aligned)
        unsigned ap[KA / 2], alp[KA / 2];
        #pragma unroll
        for (int p = 0; p < KA; p += 2) {
            float y0 = ya[p] + ybv[p] + ycv[p];
            float y1 = ya[p + 1] + ybv[p + 1] + ycv[p + 1];
            unsigned short h0 = f2bf_rne(y0), h1 = f2bf_rne(y1);
            ap[p / 2] = (unsigned)h0 | ((unsigned)h1 << 16);
            if (X3) {
                unsigned short l0 = f2bf_rne(y0 - bf2f(h0));
                unsigned short l1 = f2bf_rne(y1 - bf2f(h1));
                alp[p / 2] = (unsigned)l0 | ((unsigned)l1 << 16);
            }
        }
        if constexpr (KA == 2) {
            *(unsigned*)&Ah[buf][am][kq] = ap[0];
            if (X3) *(unsigned*)&Al[buf][am][kq] = alp[0];
        } else {
            *(uint2*)&Ah[buf][am][kq] = make_uint2(ap[0], ap[1]);
            if (X3) *(uint2*)&Al[buf][am][kq] = make_uint2(alp[0], alp[1]);
        }
        // B: pack KB bf16 (+lo) into uint2 chunks (kg*2 bytes is 16B-mult, pitch 8B-mult)
        unsigned bp[KB / 2], blp[KB / 2];
        #pragma unroll
        for (int p = 0; p < KB; p += 2) {
            unsigned short h0 = f2bf_rne(wv[p]), h1 = f2bf_rne(wv[p + 1]);
            bp[p / 2] = (unsigned)h0 | ((unsigned)h1 << 16);
            if (X3) {
                unsigned short l0 = f2bf_rne(wv[p] - bf2f(h0));
                unsigned short l1 = f2bf_rne(wv[p + 1] - bf2f(h1));
                blp[p / 2] = (unsigned)l0 | ((unsigned)l1 << 16);
            }
        }
        #pragma unroll
        for (int g = 0; g < KB / 4; ++g) {
            *(uint2*)&Bh[buf][jb][kg + 4 * g] = make_uint2(bp[2 * g], bp[2 * g + 1]);
            if (X3) *(uint2*)&Bl[buf][jb][kg + 4 * g] = make_uint2(blp[2 * g], blp[2 * g + 1]);
        }
    };

    // ---- compute mapping: 8 waves = 2m x 4n; wave tile 16m x 32n
    const int lane = t & 63, wid = t >> 6;
    const int Wm = (wid >> 2) * 16;     // 0 or 16
    const int Wn = (wid & 3) * 32;      // 0,32,64,96
    const int fr = lane & 15;
    const int g8 = (lane >> 4) * 8;

    f32x4 acc[2] = {};

    auto rd8 = [&](const unsigned short* p) -> s16x8 {
        union { s16x8 v; uint2 u[2]; } tmp;
        tmp.u[0] = *(const uint2*)(p);
        tmp.u[1] = *(const uint2*)(p + 4);
        return tmp.v;
    };

    auto compute = [&](int buf) {
        #pragma unroll
        for (int kk0 = 0; kk0 < SK; kk0 += 32) {
            s16x8 a_h = rd8(&Ah[buf][Wm + fr][kk0 + g8]);
            s16x8 b_h[2];
            #pragma unroll
            for (int nf = 0; nf < 2; ++nf) b_h[nf] = rd8(&Bh[buf][Wn + nf * 16 + fr][kk0 + g8]);
            #pragma unroll
            for (int nf = 0; nf < 2; ++nf)
                acc[nf] = __builtin_amdgcn_mfma_f32_16x16x32_bf16(a_h, b_h[nf], acc[nf], 0, 0, 0);
            if (X3) {
                s16x8 a_l = rd8(&Al[buf][Wm + fr][kk0 + g8]);
                s16x8 b_l[2];
                #pragma unroll
                for (int nf = 0; nf < 2; ++nf) b_l[nf] = rd8(&Bl[buf][Wn + nf * 16 + fr][kk0 + g8]);
                #pragma unroll
                for (int nf = 0; nf < 2; ++nf) {
                    acc[nf] = __builtin_amdgcn_mfma_f32_16x16x32_bf16(a_h, b_l[nf], acc[nf], 0, 0, 0);
                    acc[nf] = __builtin_amdgcn_mfma_f32_16x16x32_bf16(a_l, b_h[nf], acc[nf], 0, 0, 0);
                }
            }
        }
    };

    // ---- main loop over NH*SPH stages, double-buffered
    setptr(h0);
    load(0);
    store(0);
    __syncthreads();
    int cur = 0;
    for (int u = 0; u < U; ++u) {
        int un = u + 1;
        if (un < U) {
            if ((un % SPH) == 0) setptr(h0 + un / SPH);
            load(un % SPH);
        }
        compute(cur);
        if (un < U) store(cur ^ 1);
        __syncthreads();
        cur ^= 1;
    }

    // ---- epilogue: partial[b][hg][j]; D mapping col=lane&15, row=4*(lane>>4)+reg
    float* pb = partial + (((size_t)(B0 + Wm)) * GH + hg) * JD + Wn;
    #pragma unroll
    for (int nf = 0; nf < 2; ++nf)
        #pragma unroll
        for (int r = 0; r < 4; ++r) {
            int row = (lane >> 4) * 4 + r;
            pb[(size_t)row * GH * JD + nf * 16 + fr] = acc[nf][r];
        }
}

// ---------- fuse E: reduce + softmax + manip conv + manip linear + tokens ----------
__global__ __launch_bounds__(256) void k_fuseE(
        const float* __restrict__ partial, const float* __restrict__ elb,
        const float* __restrict__ Wc, const float* __restrict__ mcb,
        const float* __restrict__ mlw, const float* __restrict__ Lint,
        const float* __restrict__ mlb, int* __restrict__ tokens) {
    int b = blockIdx.x, t = threadIdx.x;
    __shared__ float S[2][128];
    __shared__ float eo[128];
    __shared__ float m3[3][64];
    __shared__ float red[128];

    int j = t & 127, hh = t >> 7;
    float s = 0.f;
    const float* pbase = partial + (size_t)b * GH * JD + j;
    for (int h = hh * 32; h < hh * 32 + 32; ++h)
        s += pbase[(size_t)h * JD];
    S[hh][j] = s;
    __syncthreads();
    if (t < 128) {
        float v = S[0][t] + S[1][t] + elb[t];
        S[0][t] = v;
        red[t] = v;
    }
    __syncthreads();
    for (int st = 64; st > 0; st >>= 1) {
        if (t < st) red[t] = fmaxf(red[t], red[t + st]);
        __syncthreads();
    }
    float mx = red[0];
    __syncthreads();
    if (t < 128) {
        float e = expf(S[0][t] - mx);
        eo[t] = e;
        red[t] = e;
    }
    __syncthreads();
    for (int st = 64; st > 0; st >>= 1) {
        if (t < st) red[t] += red[t + st];
        __syncthreads();
    }
    float inv = 1.f / red[0];
    __syncthreads();
    if (t < 128) eo[t] *= inv;
    __syncthreads();
    // manip conv values
    if (t < 192) {
        int cls = t >> 6, o = t & 63;
        float a = mcb[o];
        const float* wp = Wc + (size_t)cls * 128 * 64 + o;
        for (int i = 0; i < 128; ++i) a = fmaf(eo[i], wp[(size_t)i * 64], a);
        m3[cls][o] = fmaxf(a, 0.f);
    }
    __syncthreads();
    // manip linear + token quantization (t = j 0..255)
    float a = mlb[t];
    for (int o = 0; o < MO; ++o) {
        a = fmaf(m3[0][o], mlw[((size_t)(o * H2 + 0)) * MJ + t], a);
        a = fmaf(m3[1][o], Lint[(size_t)o * MJ + t], a);
        a = fmaf(m3[2][o], mlw[((size_t)(o * H2 + 127)) * MJ + t], a);
    }
    tokens[(size_t)b * LL + t] = ((int)floorf(fabsf(a) * 100.f)) % NV;
}

// ---------- fuse F: reduce + head linear + softmax(14) ----------
__global__ __launch_bounds__(256) void k_fuseF(
        const float* __restrict__ partial, const float* __restrict__ flb1,
        const float* __restrict__ fl2, const float* __restrict__ fb2,
        float* __restrict__ outp) {
    int b = blockIdx.x, t = threadIdx.x;
    __shared__ float S[2][128];
    __shared__ float f1[128];
    __shared__ float sl[NV];
    int j = t & 127, hh = t >> 7;
    float s = 0.f;
    const float* pbase = partial + (size_t)b * GH * JD + j;
    for (int h = hh * 32; h < hh * 32 + 32; ++h)
        s += pbase[(size_t)h * JD];
    S[hh][j] = s;
    __syncthreads();
    if (t < 128) f1[t] = S[0][t] + S[1][t] + flb1[t];
    __syncthreads();
    if (t < NV) {
        float a = fb2[t];
        for (int jj = 0; jj < 128; ++jj) a = fmaf(f1[jj], fl2[(size_t)jj * NV + t], a);
        sl[t] = a;
    }
    __syncthreads();
    if (t < NV) {
        float mx = -1e30f;
        for (int u = 0; u < NV; ++u) mx = fmaxf(mx, sl[u]);
        float ss = 0.f;
        for (int u = 0; u < NV; ++u) ss += expf(sl[u] - mx);
        outp[(size_t)b * NV + t] = expf(sl[t] - mx) / ss;
    }
}

extern "C" void kernel_launch(void* const* d_in, const int* in_sizes, int n_in,
                              void* d_out, int out_size, void* d_ws, size_t ws_size,
                              hipStream_t stream) {
    const int*   x    = (const int*)d_in[0];
    const float* eemb = (const float*)d_in[1];
    const float* ecw  = (const float*)d_in[2];
    const float* ecb  = (const float*)d_in[3];
    const float* elw  = (const float*)d_in[4];
    const float* elb  = (const float*)d_in[5];
    // d_in[6] rand_proj: provably unused (fog_of_war returns identity permutation)
    const float* mcw  = (const float*)d_in[7];
    const float* mcb  = (const float*)d_in[8];
    const float* mlw  = (const float*)d_in[9];
    const float* mlb  = (const float*)d_in[10];
    const float* femb = (const float*)d_in[11];
    const float* fcw  = (const float*)d_in[12];
    const float* fcb  = (const float*)d_in[13];
    const float* flw1 = (const float*)d_in[14];
    const float* flb1 = (const float*)d_in[15];
    const float* fl2  = (const float*)d_in[16];
    const float* fb2  = (const float*)d_in[17];
    float* outp = (float*)d_out;

    char* w = (char*)d_ws;
    size_t off = 0;
    auto alloc = [&](size_t bytes) {
        void* p = w + off;
        off = (off + bytes + 255) & ~(size_t)255;
        return p;
    };
    float* cwT    = (float*)alloc(2ull * 3 * EMBD * OC * 4);    // 3.1 MB
    float* C      = (float*)alloc(2ull * NP * 3 * OC * 4);      // 1.2 MB
    float* Wc     = (float*)alloc(3ull * 128 * 64 * 4);
    float* Lint   = (float*)alloc(64ull * MJ * 4);
    int*   tokens = (int*)alloc((size_t)BB * LL * 4);
    float* partial= (float*)alloc((size_t)BB * GH * JD * 4);    // 8.4 MB, [b][hg][j]

    const float* C_e = C;
    const float* C_f = C + (size_t)NP * 3 * OC;

    // ---- prep (cwt | manipw | lint) ----
    k_prep<<<PB_CWT + PB_MANIPW + PB_LINT, 256, 0, stream>>>(
        ecw, fcw, mcw, mlw, cwT, Wc, Lint);
    // ---- pair contributions (full K, q-batch 4, inline pair-max, cb folded) ----
    k_contrib<<<2 * 3 * 49, 256, 0, stream>>>(eemb, femb, cwT, ecb, fcb, C);

    // ---- enemy branch (bf16x3 MFMA — token path needs near-fp32) ----
    k_gemm<1, 32, 2><<<dim3(GH, 8), 512, 0, stream>>>(x, C_e, elw, partial);
    k_fuseE<<<BB, 256, 0, stream>>>(partial, elb, Wc, mcb, mlw, Lint, mlb, tokens);

    // ---- friend branch (plain bf16 MFMA, K-stage 64) ----
    k_gemm<0, 64, 2><<<dim3(GH, 8), 512, 0, stream>>>(tokens, C_f, flw1, partial);
    k_fuseF<<<BB, 256, 0, stream>>>(partial, flb1, fl2, fb2, outp);
}

// Round 11
// 81.069 us; speedup vs baseline: 1.3777x; 1.3777x over previous
//
#include <hip/hip_runtime.h>
#include <hip/hip_bf16.h>
#include <math.h>

#define BB    256   // batch
#define LL    256   // seq len
#define NV    14    // vocab
#define EMBD  512
#define H2    128   // L//2
#define OC    256   // branch conv out channels
#define NP    196   // 14*14 ordered token pairs
#define JD    128   // branch linear out
#define MO    64    // manip conv out channels
#define MJ    256   // manip linear out

// prep block ranges
#define PB_CWT    256                   // 2 br * 4 o-chunks * 32 i-chunks
#define PB_MANIPW 96
#define PB_LINT   64

using s16x8 = __attribute__((ext_vector_type(8))) short;
using f32x4 = __attribute__((ext_vector_type(4))) float;

static __device__ __forceinline__ unsigned short f2bf_rne(float f) {
    unsigned int u = __float_as_uint(f);
    unsigned int r = (u + 0x7FFFu + ((u >> 16) & 1u)) >> 16;
    return (unsigned short)r;
}
static __device__ __forceinline__ float bf2f(unsigned short h) {
    return __uint_as_float(((unsigned int)h) << 16);
}

// ---------- combined prep: cwt (LDS transpose) | manipw | lint ----------
__global__ void k_prep(const float* __restrict__ cw_e, const float* __restrict__ cw_f,
                       const float* __restrict__ mcw, const float* __restrict__ mlw,
                       float* __restrict__ cwT, float* __restrict__ Wc,
                       float* __restrict__ Lint) {
    __shared__ float T[48][66];   // cwt transpose tile
    int bid = blockIdx.x;
    int t = threadIdx.x;
    if (bid < PB_CWT) {                    // cwt: coalesced read + LDS transpose
        int cb = bid;                      // 0..255
        int ic = cb & 31;                  // i-chunk (16 i's)
        int oc = (cb >> 5) & 3;            // o-chunk (64 o's)
        int br = cb >> 7;                  // branch
        int i0 = ic * 16, o0 = oc * 64;
        const float* cw = br ? cw_f : cw_e;
        int ol = t >> 2, part = t & 3;     // o_local 0..63, i-quarter 0..3
        const float* src = cw + ((size_t)(o0 + ol) * EMBD + i0) * 9 + part * 36;
        #pragma unroll
        for (int ii = 0; ii < 4; ++ii)
            #pragma unroll
            for (int kh = 0; kh < 3; ++kh)
                T[kh * 16 + part * 4 + ii][ol] = src[ii * 9 + kh * 3 + 1];
        __syncthreads();
        int lane = t & 63, r0 = t >> 6;
        for (int rr = r0; rr < 48; rr += 4) {
            int kh = rr >> 4, il = rr & 15;
            cwT[(((size_t)(br * 3 + kh)) * EMBD + i0 + il) * OC + o0 + lane] = T[rr][lane];
        }
    } else if (bid < PB_CWT + PB_MANIPW) { // manipw
        int idx = (bid - PB_CWT) * 256 + t;
        int o = idx & 63;
        int i = (idx >> 6) & 127;
        int cls = idx >> 13;
        const float* base = mcw + ((size_t)(o * 128 + i) * 3) * 3 + 1;
        float v = 0.f;
        if (cls != 2) { v += base[3]; v += base[6]; }
        else          { v += base[0]; v += base[3]; }
        if (cls == 1)   v += base[0];
        Wc[idx] = v;
    } else {                                // lint (full interior sum)
        int o = bid - (PB_CWT + PB_MANIPW);   // 0..63
        float s = 0.f;
        for (int h = 1; h <= 126; h++)
            s += mlw[((size_t)(o * H2 + h)) * MJ + t];
        Lint[o * 256 + t] = s;
    }
}

// ---------- pair contributions, i-split x2, q-batch 4, inline pair-max ----------
__global__ __launch_bounds__(512) void k_contrib(
        const float* __restrict__ emb_e, const float* __restrict__ emb_f,
        const float* __restrict__ cwT,
        const float* __restrict__ cb_e, const float* __restrict__ cb_f,
        float* __restrict__ C) {
    int bid = blockIdx.x;               // (br*3+kh)*49+qg
    int qg = bid % 49;
    int kh = (bid / 49) % 3;
    int br = bid / 147;
    int t = threadIdx.x;
    int o = t & 255, ih = t >> 8;       // o output, i-half 0/1
    const float* emb = br ? emb_f : emb_e;

    __shared__ float Pl[4][512];
    __shared__ float Rd[4][2][256];
    for (int idx = t; idx < 4 * 512; idx += 512) {
        int row = idx >> 9, col = idx & 511;
        int q = qg * 4 + row;
        int t1 = q / NV, t2 = q % NV;
        Pl[row][col] = fmaxf(emb[t1 * EMBD + col], emb[t2 * EMBD + col]);
    }
    __syncthreads();

    const float* w = cwT + ((size_t)(br * 3 + kh) * EMBD + ih * 256) * OC + o;
    float acc[4] = {0.f, 0.f, 0.f, 0.f};
    #pragma unroll 8
    for (int i = 0; i < 256; i++) {
        float wv = w[(size_t)i * OC];
        #pragma unroll
        for (int qq = 0; qq < 4; qq++) acc[qq] = fmaf(wv, Pl[qq][ih * 256 + i], acc[qq]);
    }
    #pragma unroll
    for (int qq = 0; qq < 4; qq++) Rd[qq][ih][o] = acc[qq];
    __syncthreads();
    if (t < 256) {
        float cbv = (kh == 1) ? (br ? cb_f[o] : cb_e[o]) : 0.f;
        #pragma unroll
        for (int qq = 0; qq < 4; qq++)
            C[(((size_t)br * NP + qg * 4 + qq) * 3 + kh) * OC + o] =
                Rd[qq][0][o] + Rd[qq][1][o] + cbv;
    }
}

// ---------- MFMA GEMM: partial[b][h][j] = sum_o Y[b,h,o]*lw[(o*H2+h)*JD+j] ----------
// M-tile 64, grid (H2, 4) = 512 blocks, 8 waves 2m x 4n. SK = K per LDS stage.
// B-staging: thread owns 4 consecutive j x (SK/16) k's -> float4 loads land
// on 2 contiguous rows/instruction; LDS writes are packed b32/b64.
// X3=1: bf16 hi/lo 3-product split (near-fp32); X3=0: plain bf16.
template <int X3, int SK>
__global__ __launch_bounds__(512) void k_gemm(
        const int* __restrict__ tok, const float* __restrict__ C,
        const float* __restrict__ lw, float* __restrict__ partial) {
    __shared__ unsigned short Ah[2][64][SK + 4];
    __shared__ unsigned short Al[X3 ? 2 : 1][X3 ? 64 : 1][X3 ? SK + 4 : 1];
    __shared__ unsigned short Bh[2][128][SK + 4];
    __shared__ unsigned short Bl[X3 ? 2 : 1][X3 ? 128 : 1][X3 ? SK + 4 : 1];

    const int h  = blockIdx.x;
    const int B0 = blockIdx.y * 64;
    const int t  = threadIdx.x;
    constexpr int NST = 256 / SK;       // stages
    constexpr int KQ  = SK / 8;         // A floats per thread (per C-row)
    constexpr int KPT = SK / 16;        // B k's per thread

    // ---- A gather setup (thread: row am 0..63, k-chunk kq of KQ floats)
    const int am = t >> 3;
    const int kq = (t & 7) * KQ;
    const int* tb = tok + (size_t)(B0 + am) * LL;
    const int q1 = tb[2 * h] * NV + tb[2 * h + 1];
    const float* r1 = C + ((size_t)q1 * 3 + 1) * OC + kq;
    const float* r0 = nullptr;
    const float* r2 = nullptr;
    if (h > 0)      { int q0 = tb[2 * h - 2] * NV + tb[2 * h - 1]; r0 = C + ((size_t)q0 * 3 + 0) * OC + kq; }
    if (h < H2 - 1) { int q2 = tb[2 * h + 2] * NV + tb[2 * h + 3]; r2 = C + ((size_t)q2 * 3 + 2) * OC + kq; }

    // ---- B setup (thread: 4 j's at j0b, KPT k's at k0)
    const int j0b = (t & 31) * 4;
    const int k0  = (t >> 5) * KPT;
    const float* wsrc = lw + (((size_t)k0 * H2) + h) * JD + j0b;

    float4 ya[SK / 32], yb[SK / 32], yc[SK / 32], wv4[KPT];

    auto load = [&](int s) {
        #pragma unroll
        for (int p = 0; p < SK / 32; ++p) {
            ya[p] = *(const float4*)(r1 + s * SK + 4 * p);
            if (r0) yb[p] = *(const float4*)(r0 + s * SK + 4 * p);
            else    yb[p] = make_float4(0, 0, 0, 0);
            if (r2) yc[p] = *(const float4*)(r2 + s * SK + 4 * p);
            else    yc[p] = make_float4(0, 0, 0, 0);
        }
        #pragma unroll
        for (int kk = 0; kk < KPT; ++kk)
            wv4[kk] = *(const float4*)(wsrc + ((size_t)(s * SK) + kk) * (H2 * JD));
    };

    auto store = [&](int buf) {
        #pragma unroll
        for (int p = 0; p < SK / 32; ++p) {
            float y[4];
            y[0] = ya[p].x + yb[p].x + yc[p].x; y[1] = ya[p].y + yb[p].y + yc[p].y;
            y[2] = ya[p].z + yb[p].z + yc[p].z; y[3] = ya[p].w + yb[p].w + yc[p].w;
            unsigned short hi[4];
            #pragma unroll
            for (int e = 0; e < 4; ++e) hi[e] = f2bf_rne(y[e]);
            uint2 u;
            u.x = (unsigned)hi[0] | ((unsigned)hi[1] << 16);
            u.y = (unsigned)hi[2] | ((unsigned)hi[3] << 16);
            *(uint2*)&Ah[buf][am][kq + 4 * p] = u;
            if (X3) {
                unsigned short lo[4];
                #pragma unroll
                for (int e = 0; e < 4; ++e) lo[e] = f2bf_rne(y[e] - bf2f(hi[e]));
                uint2 v;
                v.x = (unsigned)lo[0] | ((unsigned)lo[1] << 16);
                v.y = (unsigned)lo[2] | ((unsigned)lo[3] << 16);
                *(uint2*)&Al[buf][am][kq + 4 * p] = v;
            }
        }
        // B: in-register 4j x KPT-k transpose; one packed LDS write per j
        #pragma unroll
        for (int jj = 0; jj < 4; ++jj) {
            unsigned short hb[KPT], lb[KPT];
            #pragma unroll
            for (int kk = 0; kk < KPT; ++kk) {
                float wf = ((const float*)&wv4[kk])[jj];
                hb[kk] = f2bf_rne(wf);
                if (X3) lb[kk] = f2bf_rne(wf - bf2f(hb[kk]));
            }
            if constexpr (KPT == 2) {
                *(unsigned*)&Bh[buf][j0b + jj][k0] = (unsigned)hb[0] | ((unsigned)hb[1] << 16);
                if (X3) *(unsigned*)&Bl[buf][j0b + jj][k0] = (unsigned)lb[0] | ((unsigned)lb[1] << 16);
            } else {
                uint2 u;
                u.x = (unsigned)hb[0] | ((unsigned)hb[1] << 16);
                u.y = (unsigned)hb[2] | ((unsigned)hb[3] << 16);
                *(uint2*)&Bh[buf][j0b + jj][k0] = u;
                if (X3) {
                    uint2 v;
                    v.x = (unsigned)lb[0] | ((unsigned)lb[1] << 16);
                    v.y = (unsigned)lb[2] | ((unsigned)lb[3] << 16);
                    *(uint2*)&Bl[buf][j0b + jj][k0] = v;
                }
            }
        }
    };

    // ---- compute mapping: 8 waves = 2m x 4n; wave tile 32m x 32n
    const int lane = t & 63, wid = t >> 6;
    const int Wm = (wid >> 2) * 32;     // 0 or 32
    const int Wn = (wid & 3) * 32;      // 0,32,64,96
    const int fr = lane & 15;
    const int g8 = (lane >> 4) * 8;

    f32x4 acc[2][2] = {};

    auto rd8 = [&](const unsigned short* p) -> s16x8 {
        union { s16x8 v; uint2 u[2]; } tmp;
        tmp.u[0] = *(const uint2*)(p);
        tmp.u[1] = *(const uint2*)(p + 4);
        return tmp.v;
    };

    auto compute = [&](int buf) {
        #pragma unroll
        for (int kk0 = 0; kk0 < SK; kk0 += 32) {
            s16x8 a_h[2], b_h[2];
            #pragma unroll
            for (int mf = 0; mf < 2; ++mf) a_h[mf] = rd8(&Ah[buf][Wm + mf * 16 + fr][kk0 + g8]);
            #pragma unroll
            for (int nf = 0; nf < 2; ++nf) b_h[nf] = rd8(&Bh[buf][Wn + nf * 16 + fr][kk0 + g8]);
            #pragma unroll
            for (int mf = 0; mf < 2; ++mf)
                #pragma unroll
                for (int nf = 0; nf < 2; ++nf)
                    acc[mf][nf] = __builtin_amdgcn_mfma_f32_16x16x32_bf16(a_h[mf], b_h[nf], acc[mf][nf], 0, 0, 0);
            if (X3) {
                s16x8 a_l[2], b_l[2];
                #pragma unroll
                for (int mf = 0; mf < 2; ++mf) a_l[mf] = rd8(&Al[buf][Wm + mf * 16 + fr][kk0 + g8]);
                #pragma unroll
                for (int nf = 0; nf < 2; ++nf) b_l[nf] = rd8(&Bl[buf][Wn + nf * 16 + fr][kk0 + g8]);
                #pragma unroll
                for (int mf = 0; mf < 2; ++mf)
                    #pragma unroll
                    for (int nf = 0; nf < 2; ++nf) {
                        acc[mf][nf] = __builtin_amdgcn_mfma_f32_16x16x32_bf16(a_h[mf], b_l[nf], acc[mf][nf], 0, 0, 0);
                        acc[mf][nf] = __builtin_amdgcn_mfma_f32_16x16x32_bf16(a_l[mf], b_h[nf], acc[mf][nf], 0, 0, 0);
                    }
            }
        }
    };

    // ---- main loop
    load(0);
    store(0);
    __syncthreads();
    for (int s = 0; s < NST; ++s) {
        if (s < NST - 1) load(s + 1);
        compute(s & 1);
        if (s < NST - 1) store((s + 1) & 1);
        __syncthreads();
    }

    // ---- epilogue: partial[b][h][j]; D mapping col=lane&15, row=4*(lane>>4)+reg
    float* pb = partial + (((size_t)(B0 + Wm)) * H2 + h) * JD + Wn;
    #pragma unroll
    for (int mf = 0; mf < 2; ++mf)
        #pragma unroll
        for (int nf = 0; nf < 2; ++nf)
            #pragma unroll
            for (int r = 0; r < 4; ++r) {
                int row = mf * 16 + (lane >> 4) * 4 + r;
                int col = nf * 16 + fr;
                pb[(size_t)row * H2 * JD + col] = acc[mf][nf][r];
            }
}

// ---------- fuse E: reduce + softmax + manip conv + manip linear + tokens ----------
__global__ __launch_bounds__(256) void k_fuseE(
        const float* __restrict__ partial, const float* __restrict__ elb,
        const float* __restrict__ Wc, const float* __restrict__ mcb,
        const float* __restrict__ mlw, const float* __restrict__ Lint,
        const float* __restrict__ mlb, int* __restrict__ tokens) {
    int b = blockIdx.x, t = threadIdx.x;
    __shared__ float S[2][128];
    __shared__ float eo[128];
    __shared__ float m3[3][64];
    __shared__ float red[128];

    int j = t & 127, hh = t >> 7;
    float s = 0.f;
    const float* pbase = partial + (size_t)b * H2 * JD + j;
    for (int h = hh * 64; h < hh * 64 + 64; ++h)
        s += pbase[(size_t)h * JD];
    S[hh][j] = s;
    __syncthreads();
    if (t < 128) {
        float v = S[0][t] + S[1][t] + elb[t];
        S[0][t] = v;
        red[t] = v;
    }
    __syncthreads();
    for (int st = 64; st > 0; st >>= 1) {
        if (t < st) red[t] = fmaxf(red[t], red[t + st]);
        __syncthreads();
    }
    float mx = red[0];
    __syncthreads();
    if (t < 128) {
        float e = expf(S[0][t] - mx);
        eo[t] = e;
        red[t] = e;
    }
    __syncthreads();
    for (int st = 64; st > 0; st >>= 1) {
        if (t < st) red[t] += red[t + st];
        __syncthreads();
    }
    float inv = 1.f / red[0];
    __syncthreads();
    if (t < 128) eo[t] *= inv;
    __syncthreads();
    // manip conv values
    if (t < 192) {
        int cls = t >> 6, o = t & 63;
        float a = mcb[o];
        const float* wp = Wc + (size_t)cls * 128 * 64 + o;
        for (int i = 0; i < 128; ++i) a = fmaf(eo[i], wp[(size_t)i * 64], a);
        m3[cls][o] = fmaxf(a, 0.f);
    }
    __syncthreads();
    // manip linear + token quantization (t = j 0..255)
    float a = mlb[t];
    for (int o = 0; o < MO; ++o) {
        a = fmaf(m3[0][o], mlw[((size_t)(o * H2 + 0)) * MJ + t], a);
        a = fmaf(m3[1][o], Lint[(size_t)o * MJ + t], a);
        a = fmaf(m3[2][o], mlw[((size_t)(o * H2 + 127)) * MJ + t], a);
    }
    tokens[(size_t)b * LL + t] = ((int)floorf(fabsf(a) * 100.f)) % NV;
}

// ---------- fuse F: reduce + head linear + softmax(14) ----------
__global__ __launch_bounds__(256) void k_fuseF(
        const float* __restrict__ partial, const float* __restrict__ flb1,
        const float* __restrict__ fl2, const float* __restrict__ fb2,
        float* __restrict__ outp) {
    int b = blockIdx.x, t = threadIdx.x;
    __shared__ float S[2][128];
    __shared__ float f1[128];
    __shared__ float sl[NV];
    int j = t & 127, hh = t >> 7;
    float s = 0.f;
    const float* pbase = partial + (size_t)b * H2 * JD + j;
    for (int h = hh * 64; h < hh * 64 + 64; ++h)
        s += pbase[(size_t)h * JD];
    S[hh][j] = s;
    __syncthreads();
    if (t < 128) f1[t] = S[0][t] + S[1][t] + flb1[t];
    __syncthreads();
    if (t < NV) {
        float a = fb2[t];
        for (int jj = 0; jj < 128; ++jj) a = fmaf(f1[jj], fl2[(size_t)jj * NV + t], a);
        sl[t] = a;
    }
    __syncthreads();
    if (t < NV) {
        float mx = -1e30f;
        for (int u = 0; u < NV; ++u) mx = fmaxf(mx, sl[u]);
        float ss = 0.f;
        for (int u = 0; u < NV; ++u) ss += expf(sl[u] - mx);
        outp[(size_t)b * NV + t] = expf(sl[t] - mx) / ss;
    }
}

extern "C" void kernel_launch(void* const* d_in, const int* in_sizes, int n_in,
                              void* d_out, int out_size, void* d_ws, size_t ws_size,
                              hipStream_t stream) {
    const int*   x    = (const int*)d_in[0];
    const float* eemb = (const float*)d_in[1];
    const float* ecw  = (const float*)d_in[2];
    const float* ecb  = (const float*)d_in[3];
    const float* elw  = (const float*)d_in[4];
    const float* elb  = (const float*)d_in[5];
    // d_in[6] rand_proj: provably unused (fog_of_war returns identity permutation)
    const float* mcw  = (const float*)d_in[7];
    const float* mcb  = (const float*)d_in[8];
    const float* mlw  = (const float*)d_in[9];
    const float* mlb  = (const float*)d_in[10];
    const float* femb = (const float*)d_in[11];
    const float* fcw  = (const float*)d_in[12];
    const float* fcb  = (const float*)d_in[13];
    const float* flw1 = (const float*)d_in[14];
    const float* flb1 = (const float*)d_in[15];
    const float* fl2  = (const float*)d_in[16];
    const float* fb2  = (const float*)d_in[17];
    float* outp = (float*)d_out;

    char* w = (char*)d_ws;
    size_t off = 0;
    auto alloc = [&](size_t bytes) {
        void* p = w + off;
        off = (off + bytes + 255) & ~(size_t)255;
        return p;
    };
    float* cwT    = (float*)alloc(2ull * 3 * EMBD * OC * 4);    // 3.1 MB
    float* C      = (float*)alloc(2ull * NP * 3 * OC * 4);      // 1.2 MB
    float* Wc     = (float*)alloc(3ull * 128 * 64 * 4);
    float* Lint   = (float*)alloc(64ull * MJ * 4);
    int*   tokens = (int*)alloc((size_t)BB * LL * 4);
    float* partial= (float*)alloc((size_t)BB * H2 * JD * 4);    // 16.8 MB, [b][h][j]

    const float* C_e = C;
    const float* C_f = C + (size_t)NP * 3 * OC;

    // ---- prep (cwt | manipw | lint) ----
    k_prep<<<PB_CWT + PB_MANIPW + PB_LINT, 256, 0, stream>>>(
        ecw, fcw, mcw, mlw, cwT, Wc, Lint);
    // ---- pair contributions (i-split x2, q-batch 4, inline pair-max, cb folded) ----
    k_contrib<<<2 * 3 * 49, 512, 0, stream>>>(eemb, femb, cwT, ecb, fcb, C);

    // ---- enemy branch (bf16x3 MFMA — token path needs near-fp32) ----
    k_gemm<1, 32><<<dim3(H2, 4), 512, 0, stream>>>(x, C_e, elw, partial);
    k_fuseE<<<BB, 256, 0, stream>>>(partial, elb, Wc, mcb, mlw, Lint, mlb, tokens);

    // ---- friend branch (plain bf16 MFMA, K-stage 64) ----
    k_gemm<0, 64><<<dim3(H2, 4), 512, 0, stream>>>(tokens, C_f, flw1, partial);
    k_fuseF<<<BB, 256, 0, stream>>>(partial, flb1, fl2, fb2, outp);
}